// Round 5
// baseline (989.586 us; speedup 1.0000x reference)
//
#include <hip/hip_runtime.h>
#include <math.h>

// ---------------------------------------------------------------------------
// GAT 3-layer + pooling, XCD-sharded-gather edition.
//  - GEMMs: fp16 MFMA 128x128x32, outputs written CHUNK-MAJOR:
//      feat_c[chunk][node][64ch]  (chunk = 64 channels = 128B rows).
//  - Aggregation: per-layer, (1) edge_weight_kernel precomputes normalized
//    softmax weights wexp[h][pos] (f16, head-major); (2) agg_chunk_kernel:
//    chunk = blockIdx % 8 -> chunk pinned to one XCD (round-robin mapping),
//    so each XCD's gather working set is one 2.56MB chunk that FITS ITS L2.
//    Kills the 8x cross-XCD compulsory re-fetch of feat (round-3/4 FETCH
//    floor was 8 XCD x feat_size).
//  - Layer-2 residual in a separate row-major buffer (round-4's interleave
//    raised FETCH 244->330MB; reverted).
// ---------------------------------------------------------------------------

typedef _Float16 f16;
typedef __attribute__((ext_vector_type(8))) _Float16 half8;
typedef __attribute__((ext_vector_type(4))) _Float16 half4;
typedef __attribute__((ext_vector_type(4))) float float4v;

#define M_PAD 20096        // 20000 rounded up to 128
#define CHSTRIDE ((size_t)M_PAD * 64)

__device__ inline void gload_lds16(const void* g, void* l) {
    __builtin_amdgcn_global_load_lds((const __attribute__((address_space(1))) unsigned*)g,
                                     (__attribute__((address_space(3))) unsigned*)l,
                                     16, 0, 0);
}

// ----------------------------- CSR construction ---------------------------

__global__ __launch_bounds__(256) void deg_kernel(const int* __restrict__ dst,
                                                  int* __restrict__ deg, int E) {
    int e = blockIdx.x * 256 + threadIdx.x;
    if (e < E) atomicAdd(&deg[dst[e]], 1);
}

__global__ __launch_bounds__(1024) void scan_kernel(const int* __restrict__ deg,
                                                    int* __restrict__ row_off, int n) {
    __shared__ int sums[1024];
    int t = threadIdx.x;
    int CH = (n + 1023) >> 10;
    int base = t * CH;
    int s = 0;
    for (int i = 0; i < CH; ++i) { int idx = base + i; if (idx < n) s += deg[idx]; }
    sums[t] = s;
    __syncthreads();
    for (int off = 1; off < 1024; off <<= 1) {
        int v = (t >= off) ? sums[t - off] : 0;
        __syncthreads();
        sums[t] += v;
        __syncthreads();
    }
    int run = (t == 0) ? 0 : sums[t - 1];
    for (int i = 0; i < CH; ++i) {
        int idx = base + i;
        if (idx < n) { row_off[idx] = run; run += deg[idx]; }
    }
    if (t == 1023) row_off[n] = run;
}

__global__ __launch_bounds__(256) void fill_kernel(const int* __restrict__ src,
                                                   const int* __restrict__ dst,
                                                   const int* __restrict__ row_off,
                                                   int* __restrict__ fill,
                                                   int* __restrict__ csr_src, int E) {
    int e = blockIdx.x * 256 + threadIdx.x;
    if (e < E) {
        int d = dst[e];
        int pos = row_off[d] + atomicAdd(&fill[d], 1);
        csr_src[pos] = src[e];
    }
}

// ------------------------------ converts -----------------------------------

__global__ __launch_bounds__(256) void cvt_pad_kernel(const float* __restrict__ x,
                                                      f16* __restrict__ y,
                                                      long n_valid, long n_total) {
    long i = ((long)blockIdx.x * 256 + threadIdx.x) * 4;
    if (i >= n_total) return;
    float4 v = make_float4(0.f, 0.f, 0.f, 0.f);
    if (i < n_valid) v = *(const float4*)&x[i];
    half4 o; o[0] = (f16)v.x; o[1] = (f16)v.y; o[2] = (f16)v.z; o[3] = (f16)v.w;
    *(half4*)&y[i] = o;
}

// Wt[n][k] = (f16) W[k][n].  K,N multiples of 32.  block (32,8)
__global__ __launch_bounds__(256) void transpose_cvt_kernel(const float* __restrict__ W,
                                                            f16* __restrict__ Wt,
                                                            int K, int N) {
    __shared__ float tile[32][33];
    int n0 = blockIdx.x * 32, k0 = blockIdx.y * 32;
    int tx = threadIdx.x, ty = threadIdx.y;
#pragma unroll
    for (int i = 0; i < 32; i += 8)
        tile[ty + i][tx] = W[(size_t)(k0 + ty + i) * N + n0 + tx];
    __syncthreads();
#pragma unroll
    for (int i = 0; i < 32; i += 8)
        Wt[(size_t)(n0 + ty + i) * K + k0 + tx] = (f16)tile[tx][ty + i];
}

// ------------------------------ fp16 MFMA GEMM -----------------------------
// Cols < nchunk go to chunk-major Cc[chunk][row][64]; cols >= nchunk go to
// row-major Cr[row][N-nchunk].

__global__ __launch_bounds__(256) void gemm16_kernel(const f16* __restrict__ A,
                                                     const f16* __restrict__ Bt,
                                                     f16* __restrict__ Cc,
                                                     f16* __restrict__ Cr,
                                                     int N, int K, int nchunk) {
    __shared__ f16 As[128 * 32];
    __shared__ f16 Bs[128 * 32];
    int t = threadIdx.x;
    int w = t >> 6;
    int l = t & 63;
    size_t bm = (size_t)blockIdx.y * 128;
    int bn = blockIdx.x * 128;
    int wm = (w & 1) * 64;
    int wn = (w >> 1) * 64;

    int srow = t >> 2;
    int scol = (t & 3) * 8;
    const f16* ag0 = A + (bm + srow) * K + scol;
    const f16* ag1 = A + (bm + 64 + srow) * K + scol;
    const f16* bg0 = Bt + (size_t)(bn + srow) * K + scol;
    const f16* bg1 = Bt + (size_t)(bn + 64 + srow) * K + scol;
    f16* al0 = As + t * 8;
    f16* al1 = As + 2048 + t * 8;
    f16* bl0 = Bs + t * 8;
    f16* bl1 = Bs + 2048 + t * 8;

    float4v acc[4][4];
#pragma unroll
    for (int i = 0; i < 4; ++i)
#pragma unroll
        for (int j = 0; j < 4; ++j) acc[i][j] = (float4v)(0.f);

    int ml = l & 15, q = l >> 4;
    const f16* ap = As + (wm + ml) * 32 + q * 8;
    const f16* bp = Bs + (wn + ml) * 32 + q * 8;

    for (int k0 = 0; k0 < K; k0 += 32) {
        gload_lds16(ag0 + k0, al0);
        gload_lds16(ag1 + k0, al1);
        gload_lds16(bg0 + k0, bl0);
        gload_lds16(bg1 + k0, bl1);
        __syncthreads();
        half8 af[4], bf[4];
#pragma unroll
        for (int mt = 0; mt < 4; ++mt) af[mt] = *(const half8*)(ap + mt * 16 * 32);
#pragma unroll
        for (int nt = 0; nt < 4; ++nt) bf[nt] = *(const half8*)(bp + nt * 16 * 32);
#pragma unroll
        for (int mt = 0; mt < 4; ++mt)
#pragma unroll
            for (int nt = 0; nt < 4; ++nt)
                acc[mt][nt] = __builtin_amdgcn_mfma_f32_16x16x32_f16(bf[nt], af[mt],
                                                                     acc[mt][nt], 0, 0, 0);
        __syncthreads();
    }
#pragma unroll
    for (int mt = 0; mt < 4; ++mt) {
        size_t row = bm + wm + mt * 16 + ml;
#pragma unroll
        for (int nt = 0; nt < 4; ++nt) {
            half4 hv;
#pragma unroll
            for (int r = 0; r < 4; ++r) hv[r] = (f16)acc[mt][nt][r];
            int col = bn + wn + nt * 16 + q * 4;
            if (col < nchunk) {
                *(half4*)&Cc[(size_t)(col >> 6) * CHSTRIDE + row * 64 + (col & 63)] = hv;
            } else {
                *(half4*)&Cr[row * (size_t)(N - nchunk) + (col - nchunk)] = hv;
            }
        }
    }
}

// --------------------------- attention logits ------------------------------
// chunk-major feat input; head h = chunks 2h, 2h+1.

__global__ void attn_logits_kernel(const f16* __restrict__ featc,
                                   const float* __restrict__ al,
                                   const float* __restrict__ ar,
                                   float* __restrict__ el8, float* __restrict__ er8) {
    int v = blockIdx.x;
    int h = threadIdx.y;
    int lane = threadIdx.x;
    float f0 = (float)featc[(size_t)(2 * h) * CHSTRIDE + (size_t)v * 64 + lane];
    float f1 = (float)featc[(size_t)(2 * h + 1) * CHSTRIDE + (size_t)v * 64 + lane];
    float sl = f0 * al[h * 128 + lane] + f1 * al[h * 128 + 64 + lane];
    float sr = f0 * ar[h * 128 + lane] + f1 * ar[h * 128 + 64 + lane];
#pragma unroll
    for (int off = 32; off > 0; off >>= 1) {
        sl += __shfl_down(sl, off, 64);
        sr += __shfl_down(sr, off, 64);
    }
    if (lane == 0) { el8[(size_t)v * 8 + h] = sl; er8[(size_t)v * 8 + h] = sr; }
}

// ------------------------ edge softmax weights -----------------------------
// One wave per node. Computes normalized softmax weights into head-major
// wexp[h*E + pos] (f16). Two passes over the (short) edge list.

__global__ __launch_bounds__(256, 8) void edge_weight_kernel(
        const float* __restrict__ el8, const float* __restrict__ er8,
        const int* __restrict__ row_off, const int* __restrict__ csr_src,
        f16* __restrict__ wexp, int H, int n, int E) {
    int wid = threadIdx.x >> 6, lane = threadIdx.x & 63;
    for (int v = blockIdx.x * 4 + wid; v < n; v += 8192) {
        float era[6];
#pragma unroll
        for (int h = 0; h < 6; ++h) era[h] = (h < H) ? er8[(size_t)v * 8 + h] : 0.f;
        int beg = row_off[v], end = row_off[v + 1];
        float lsum[6] = {0.f, 0.f, 0.f, 0.f, 0.f, 0.f};
        for (int pos = beg; pos < end; pos += 64) {
            int cnt = min(64, end - pos);
            int s_l = (lane < cnt) ? csr_src[pos + lane] : 0;
            float4 a = *(const float4*)&el8[(size_t)s_l * 8];
            float2 bq = *(const float2*)&el8[(size_t)s_l * 8 + 4];
            float ee[6] = {a.x, a.y, a.z, a.w, bq.x, bq.y};
#pragma unroll
            for (int h = 0; h < 6; ++h) {
                if (h < H) {
                    float lg = ee[h] + era[h];
                    lg = (lg >= 0.f) ? lg : 0.2f * lg;
                    float wv = __expf(lg);
                    if (lane >= cnt) wv = 0.f;
                    lsum[h] += wv;
                    if (lane < cnt) wexp[(size_t)h * E + pos + lane] = (f16)wv;
                }
            }
        }
#pragma unroll
        for (int h = 0; h < 6; ++h)
#pragma unroll
            for (int off = 32; off >= 1; off >>= 1)
                lsum[h] += __shfl_xor(lsum[h], off, 64);
        float inv[6];
#pragma unroll
        for (int h = 0; h < 6; ++h) inv[h] = 1.f / fmaxf(lsum[h], 1e-9f);
        for (int pos = beg; pos < end; pos += 64) {
            int cnt = min(64, end - pos);
            if (lane < cnt) {
#pragma unroll
                for (int h = 0; h < 6; ++h) {
                    if (h < H) {
                        size_t ix = (size_t)h * E + pos + lane;
                        wexp[ix] = (f16)((float)wexp[ix] * inv[h]);
                    }
                }
            }
        }
    }
}

// ------------------------ chunk-sharded aggregation ------------------------
// chunk = blockIdx % 8 (round-robin block->XCD): each XCD's gather set is
// one 2.56MB chunk -> L2-resident. Phase 2 (chunks 8..11, layer 2 only)
// runs at 2x block parallelism on XCD pairs.

__device__ __forceinline__ void agg_chunk_body(
        const f16* __restrict__ featc, const f16* __restrict__ wexp,
        const int* __restrict__ row_off, const int* __restrict__ csr_src,
        const f16* __restrict__ res, const float* __restrict__ bias,
        f16* __restrict__ out16, float* __restrict__ out32,
        int n, int width, int E, int act,
        int chunk, int bic, int vstride, int wid, int lane) {
    const f16* fc = featc + (size_t)chunk * CHSTRIDE;
    const f16* wh = wexp + (size_t)(chunk >> 1) * E;
    int cb = chunk * 64 + lane;
    float bc = bias[cb];
    for (int v = bic * 4 + wid; v < n; v += vstride) {
        int beg = row_off[v], end = row_off[v + 1];
        float acc = 0.f;
        for (int pos = beg; pos < end; pos += 64) {
            int cnt = min(64, end - pos);
            int s_l = 0; float w_l = 0.f;
            if (lane < cnt) {
                s_l = csr_src[pos + lane];
                w_l = (float)wh[pos + lane];
            }
#pragma unroll 4
            for (int i = 0; i < cnt; ++i) {
                int s = __shfl(s_l, i, 64);
                float wv = __shfl(w_l, i, 64);
                acc += wv * (float)fc[(size_t)s * 64 + lane];
            }
        }
        float o = acc;
        if (res) o += (float)res[(size_t)v * width + cb];
        o += bc;
        if (act) o = (o > 0.f) ? o : expm1f(o);
        size_t oidx = (size_t)v * width + cb;
        if (out16) out16[oidx] = (f16)o;
        else out32[oidx] = o;
    }
}

__global__ __launch_bounds__(256, 8) void agg_chunk_kernel(
        const f16* __restrict__ featc, const f16* __restrict__ wexp,
        const int* __restrict__ row_off, const int* __restrict__ csr_src,
        const f16* __restrict__ res, const float* __restrict__ bias,
        f16* __restrict__ out16, float* __restrict__ out32,
        int n, int nchunks, int width, int E, int act) {
    int wid = threadIdx.x >> 6, lane = threadIdx.x & 63;
    int b = blockIdx.x;
    // phase 1: chunks 0..7, 256 blocks each (stride 1024 waves)
    agg_chunk_body(featc, wexp, row_off, csr_src, res, bias, out16, out32,
                   n, width, E, act, b & 7, b >> 3, 1024, wid, lane);
    // phase 2: chunks 8..nchunks-1 at 512 blocks each (stride 2048 waves)
    if (nchunks > 8) {
        int chunk = 8 + (b & 3);
        if (chunk < nchunks)
            agg_chunk_body(featc, wexp, row_off, csr_src, res, bias, out16, out32,
                           n, width, E, act, chunk, b >> 2, 2048, wid, lane);
    }
}

// ------------------------- head-mean + graph pooling -----------------------

__global__ void mean_pool_kernel(const float* __restrict__ x3,
                                 const int* __restrict__ gid,
                                 float* __restrict__ local,
                                 float* __restrict__ pooled,
                                 float* __restrict__ cnt) {
    int v = blockIdx.x;
    int d = threadIdx.x;
    const float* p = x3 + (size_t)v * 768;
    float s = 0.f;
#pragma unroll
    for (int h = 0; h < 6; ++h) s += p[h * 128 + d];
    s *= (1.f / 6.f);
    local[(size_t)v * 128 + d] = s;
    int g = gid[v];
    atomicAdd(&pooled[g * 128 + d], s);
    if (d == 0) atomicAdd(&cnt[g], 1.0f);
}

__global__ void final_mlp_kernel(const float* __restrict__ pooled,
                                 const float* __restrict__ cnt,
                                 const float* __restrict__ Wm,
                                 const float* __restrict__ bm,
                                 float* __restrict__ gout) {
    int g = blockIdx.x;
    int j = threadIdx.x;
    __shared__ float p[128];
    float c = fmaxf(cnt[g], 1.0f);
    p[j] = pooled[g * 128 + j] / c;
    __syncthreads();
    float s = 0.f;
#pragma unroll 16
    for (int k = 0; k < 128; ++k) s += p[k] * Wm[k * 128 + j];
    gout[g * 128 + j] = s + bm[j];
}

// --------------------------------- driver ----------------------------------

extern "C" void kernel_launch(void* const* d_in, const int* in_sizes, int n_in,
                              void* d_out, int out_size, void* d_ws, size_t ws_size,
                              hipStream_t stream) {
    const float* h     = (const float*)d_in[0];
    const int*   src   = (const int*)d_in[2];
    const int*   dst   = (const int*)d_in[3];
    const int*   gid   = (const int*)d_in[4];
    const float* W0    = (const float*)d_in[5];
    const float* al0   = (const float*)d_in[6];
    const float* ar0   = (const float*)d_in[7];
    const float* b0    = (const float*)d_in[8];
    const float* W1    = (const float*)d_in[9];
    const float* al1   = (const float*)d_in[10];
    const float* ar1   = (const float*)d_in[11];
    const float* b1    = (const float*)d_in[12];
    const float* W2    = (const float*)d_in[13];
    const float* al2   = (const float*)d_in[14];
    const float* ar2   = (const float*)d_in[15];
    const float* b2    = (const float*)d_in[16];
    const float* resW2 = (const float*)d_in[17];
    const float* Wm    = (const float*)d_in[18];
    const float* bm    = (const float*)d_in[19];

    const int n = in_sizes[0] / 128;   // 20000
    const int E = in_sizes[2];         // 320000

    size_t off = 0;
    auto take = [&](size_t bytes) -> void* {
        void* p = (char*)d_ws + off;
        off = (off + bytes + 255) & ~(size_t)255;
        return p;
    };
    f16* h16     = (f16*)take((size_t)M_PAD * 128 * 2);
    f16* Wt0     = (f16*)take((size_t)512 * 128 * 2);
    f16* Wt1     = (f16*)take((size_t)512 * 512 * 2);
    f16* Wt2cat  = (f16*)take((size_t)1536 * 512 * 2);   // [W2^T ; resW2^T]
    f16* featc   = (f16*)take((size_t)12 * CHSTRIDE * 2); // chunk-major feat (<=12 chunks)
    f16* res2    = (f16*)take((size_t)M_PAD * 768 * 2);   // row-major residual for L2
    f16* x1_16   = (f16*)take((size_t)M_PAD * 512 * 2);
    f16* x2_16   = (f16*)take((size_t)M_PAD * 512 * 2);
    float* x3    = (float*)take((size_t)n * 768 * 4);
    f16* wexp    = (f16*)take((size_t)6 * E * 2);
    float* el8   = (float*)take((size_t)n * 8 * 4);
    float* er8   = (float*)take((size_t)n * 8 * 4);
    int* deg     = (int*)take((size_t)n * 4);
    int* row_off = (int*)take((size_t)(n + 1) * 4);
    int* fillc   = (int*)take((size_t)n * 4);
    int* csr_src = (int*)take((size_t)E * 4);
    float* pooled = (float*)take(64 * 128 * 4);
    float* cnt    = (float*)take(64 * 4);

    float* out_local  = (float*)d_out;
    float* out_global = (float*)d_out + (size_t)n * 128;

    hipMemsetAsync(deg, 0, (size_t)n * 4, stream);
    hipMemsetAsync(fillc, 0, (size_t)n * 4, stream);
    hipMemsetAsync(pooled, 0, 64 * 128 * 4, stream);
    hipMemsetAsync(cnt, 0, 64 * 4, stream);
    hipMemsetAsync(x1_16 + (size_t)n * 512, 0, (size_t)(M_PAD - n) * 512 * 2, stream);
    hipMemsetAsync(x2_16 + (size_t)n * 512, 0, (size_t)(M_PAD - n) * 512 * 2, stream);

    {
        long nv = (long)n * 128, nt = (long)M_PAD * 128;
        cvt_pad_kernel<<<(int)((nt / 4 + 255) / 256), 256, 0, stream>>>(h, h16, nv, nt);
    }
    transpose_cvt_kernel<<<dim3(512 / 32, 128 / 32), dim3(32, 8), 0, stream>>>(W0, Wt0, 128, 512);
    transpose_cvt_kernel<<<dim3(512 / 32, 512 / 32), dim3(32, 8), 0, stream>>>(W1, Wt1, 512, 512);
    transpose_cvt_kernel<<<dim3(768 / 32, 512 / 32), dim3(32, 8), 0, stream>>>(W2, Wt2cat, 512, 768);
    transpose_cvt_kernel<<<dim3(768 / 32, 512 / 32), dim3(32, 8), 0, stream>>>(resW2, Wt2cat + (size_t)768 * 512, 512, 768);

    deg_kernel<<<(E + 255) / 256, 256, 0, stream>>>(dst, deg, E);
    scan_kernel<<<1, 1024, 0, stream>>>(deg, row_off, n);
    fill_kernel<<<(E + 255) / 256, 256, 0, stream>>>(src, dst, row_off, fillc, csr_src, E);

    const int gy = M_PAD / 128;

    // --- layer 0: feat = h16 @ W0 (512 -> 8 chunks), H=4, no res, elu ---
    gemm16_kernel<<<dim3(512 / 128, gy), 256, 0, stream>>>(h16, Wt0, featc, nullptr, 512, 128, 512);
    attn_logits_kernel<<<n, dim3(64, 4), 0, stream>>>(featc, al0, ar0, el8, er8);
    edge_weight_kernel<<<2048, 256, 0, stream>>>(el8, er8, row_off, csr_src, wexp, 4, n, E);
    agg_chunk_kernel<<<2048, 256, 0, stream>>>(featc, wexp, row_off, csr_src,
                                               nullptr, b0, x1_16, nullptr, n, 8, 512, E, 1);
    // --- layer 1: feat = x1 @ W1, H=4, identity res, elu ---
    gemm16_kernel<<<dim3(512 / 128, gy), 256, 0, stream>>>(x1_16, Wt1, featc, nullptr, 512, 512, 512);
    attn_logits_kernel<<<n, dim3(64, 4), 0, stream>>>(featc, al1, ar1, el8, er8);
    edge_weight_kernel<<<2048, 256, 0, stream>>>(el8, er8, row_off, csr_src, wexp, 4, n, E);
    agg_chunk_kernel<<<2048, 256, 0, stream>>>(featc, wexp, row_off, csr_src,
                                               x1_16, b1, x2_16, nullptr, n, 8, 512, E, 1);
    // --- layer 2: [feat(12 chunks) | res2(row-major)] = x2 @ [W2|resW2], H=6 ---
    gemm16_kernel<<<dim3(1536 / 128, gy), 256, 0, stream>>>(x2_16, Wt2cat, featc, res2, 1536, 512, 768);
    attn_logits_kernel<<<n, dim3(64, 6), 0, stream>>>(featc, al2, ar2, el8, er8);
    edge_weight_kernel<<<2048, 256, 0, stream>>>(el8, er8, row_off, csr_src, wexp, 6, n, E);
    agg_chunk_kernel<<<2048, 256, 0, stream>>>(featc, wexp, row_off, csr_src,
                                               res2, b2, nullptr, x3, n, 12, 768, E, 0);
    // --- head mean + pooling + final MLP ---
    mean_pool_kernel<<<n, 128, 0, stream>>>(x3, gid, out_local, pooled, cnt);
    final_mlp_kernel<<<64, 128, 0, stream>>>(pooled, cnt, Wm, bm, out_global);
}

// Round 6
// 859.356 us; speedup vs baseline: 1.1515x; 1.1515x over previous
//
#include <hip/hip_runtime.h>
#include <math.h>

// ---------------------------------------------------------------------------
// GAT 3-layer + pooling, XCD-sharded gather v2.
//  - feat stored CHUNK-MAJOR: featc[chunk][node][64ch] (128B rows);
//    chunk = blockIdx%8 pins each chunk to one XCD's L2 (2.56MB < 4MB).
//    (Round-5 result: FETCH 330->65MB; this round fixes its per-edge
//     overhead: 8 edges per half8 gather instr, LDS-staged src/weights.)
//  - edge_weight: single pass, unnormalized f32 weights + inv8[v][h] factor.
//  - GEMMs: fp16 MFMA 128x128x32, chunk-major scatter stores.
// ---------------------------------------------------------------------------

typedef _Float16 f16;
typedef __attribute__((ext_vector_type(8))) _Float16 half8;
typedef __attribute__((ext_vector_type(4))) _Float16 half4;
typedef __attribute__((ext_vector_type(4))) float float4v;

#define M_PAD 20096        // 20000 rounded up to 128
#define CHSTRIDE ((size_t)M_PAD * 64)

__device__ inline void gload_lds16(const void* g, void* l) {
    __builtin_amdgcn_global_load_lds((const __attribute__((address_space(1))) unsigned*)g,
                                     (__attribute__((address_space(3))) unsigned*)l,
                                     16, 0, 0);
}

// ----------------------------- CSR construction ---------------------------

__global__ __launch_bounds__(256) void deg_kernel(const int* __restrict__ dst,
                                                  int* __restrict__ deg, int E) {
    int e = blockIdx.x * 256 + threadIdx.x;
    if (e < E) atomicAdd(&deg[dst[e]], 1);
}

__global__ __launch_bounds__(1024) void scan_kernel(const int* __restrict__ deg,
                                                    int* __restrict__ row_off, int n) {
    __shared__ int sums[1024];
    int t = threadIdx.x;
    int CH = (n + 1023) >> 10;
    int base = t * CH;
    int s = 0;
    for (int i = 0; i < CH; ++i) { int idx = base + i; if (idx < n) s += deg[idx]; }
    sums[t] = s;
    __syncthreads();
    for (int off = 1; off < 1024; off <<= 1) {
        int v = (t >= off) ? sums[t - off] : 0;
        __syncthreads();
        sums[t] += v;
        __syncthreads();
    }
    int run = (t == 0) ? 0 : sums[t - 1];
    for (int i = 0; i < CH; ++i) {
        int idx = base + i;
        if (idx < n) { row_off[idx] = run; run += deg[idx]; }
    }
    if (t == 1023) row_off[n] = run;
}

__global__ __launch_bounds__(256) void fill_kernel(const int* __restrict__ src,
                                                   const int* __restrict__ dst,
                                                   const int* __restrict__ row_off,
                                                   int* __restrict__ fill,
                                                   int* __restrict__ csr_src, int E) {
    int e = blockIdx.x * 256 + threadIdx.x;
    if (e < E) {
        int d = dst[e];
        int pos = row_off[d] + atomicAdd(&fill[d], 1);
        csr_src[pos] = src[e];
    }
}

// ------------------------------ converts -----------------------------------

__global__ __launch_bounds__(256) void cvt_pad_kernel(const float* __restrict__ x,
                                                      f16* __restrict__ y,
                                                      long n_valid, long n_total) {
    long i = ((long)blockIdx.x * 256 + threadIdx.x) * 4;
    if (i >= n_total) return;
    float4 v = make_float4(0.f, 0.f, 0.f, 0.f);
    if (i < n_valid) v = *(const float4*)&x[i];
    half4 o; o[0] = (f16)v.x; o[1] = (f16)v.y; o[2] = (f16)v.z; o[3] = (f16)v.w;
    *(half4*)&y[i] = o;
}

// Wt[n][k] = (f16) W[k][n].  K,N multiples of 32.  block (32,8)
__global__ __launch_bounds__(256) void transpose_cvt_kernel(const float* __restrict__ W,
                                                            f16* __restrict__ Wt,
                                                            int K, int N) {
    __shared__ float tile[32][33];
    int n0 = blockIdx.x * 32, k0 = blockIdx.y * 32;
    int tx = threadIdx.x, ty = threadIdx.y;
#pragma unroll
    for (int i = 0; i < 32; i += 8)
        tile[ty + i][tx] = W[(size_t)(k0 + ty + i) * N + n0 + tx];
    __syncthreads();
#pragma unroll
    for (int i = 0; i < 32; i += 8)
        Wt[(size_t)(n0 + ty + i) * K + k0 + tx] = (f16)tile[tx][ty + i];
}

// ------------------------------ fp16 MFMA GEMM -----------------------------
// Cols < nchunk -> chunk-major Cc[chunk][row][64]; cols >= nchunk -> row-major Cr.

__global__ __launch_bounds__(256) void gemm16_kernel(const f16* __restrict__ A,
                                                     const f16* __restrict__ Bt,
                                                     f16* __restrict__ Cc,
                                                     f16* __restrict__ Cr,
                                                     int N, int K, int nchunk) {
    __shared__ f16 As[128 * 32];
    __shared__ f16 Bs[128 * 32];
    int t = threadIdx.x;
    int w = t >> 6;
    int l = t & 63;
    size_t bm = (size_t)blockIdx.y * 128;
    int bn = blockIdx.x * 128;
    int wm = (w & 1) * 64;
    int wn = (w >> 1) * 64;

    int srow = t >> 2;
    int scol = (t & 3) * 8;
    const f16* ag0 = A + (bm + srow) * K + scol;
    const f16* ag1 = A + (bm + 64 + srow) * K + scol;
    const f16* bg0 = Bt + (size_t)(bn + srow) * K + scol;
    const f16* bg1 = Bt + (size_t)(bn + 64 + srow) * K + scol;
    f16* al0 = As + t * 8;
    f16* al1 = As + 2048 + t * 8;
    f16* bl0 = Bs + t * 8;
    f16* bl1 = Bs + 2048 + t * 8;

    float4v acc[4][4];
#pragma unroll
    for (int i = 0; i < 4; ++i)
#pragma unroll
        for (int j = 0; j < 4; ++j) acc[i][j] = (float4v)(0.f);

    int ml = l & 15, q = l >> 4;
    const f16* ap = As + (wm + ml) * 32 + q * 8;
    const f16* bp = Bs + (wn + ml) * 32 + q * 8;

    for (int k0 = 0; k0 < K; k0 += 32) {
        gload_lds16(ag0 + k0, al0);
        gload_lds16(ag1 + k0, al1);
        gload_lds16(bg0 + k0, bl0);
        gload_lds16(bg1 + k0, bl1);
        __syncthreads();
        half8 af[4], bf[4];
#pragma unroll
        for (int mt = 0; mt < 4; ++mt) af[mt] = *(const half8*)(ap + mt * 16 * 32);
#pragma unroll
        for (int nt = 0; nt < 4; ++nt) bf[nt] = *(const half8*)(bp + nt * 16 * 32);
#pragma unroll
        for (int mt = 0; mt < 4; ++mt)
#pragma unroll
            for (int nt = 0; nt < 4; ++nt)
                acc[mt][nt] = __builtin_amdgcn_mfma_f32_16x16x32_f16(bf[nt], af[mt],
                                                                     acc[mt][nt], 0, 0, 0);
        __syncthreads();
    }
#pragma unroll
    for (int mt = 0; mt < 4; ++mt) {
        size_t row = bm + wm + mt * 16 + ml;
#pragma unroll
        for (int nt = 0; nt < 4; ++nt) {
            half4 hv;
#pragma unroll
            for (int r = 0; r < 4; ++r) hv[r] = (f16)acc[mt][nt][r];
            int col = bn + wn + nt * 16 + q * 4;
            if (col < nchunk) {
                *(half4*)&Cc[(size_t)(col >> 6) * CHSTRIDE + row * 64 + (col & 63)] = hv;
            } else {
                *(half4*)&Cr[row * (size_t)(N - nchunk) + (col - nchunk)] = hv;
            }
        }
    }
}

// --------------------------- attention logits ------------------------------
// chunk-major feat input; head h = chunks 2h, 2h+1.

__global__ void attn_logits_kernel(const f16* __restrict__ featc,
                                   const float* __restrict__ al,
                                   const float* __restrict__ ar,
                                   float* __restrict__ el8, float* __restrict__ er8) {
    int v = blockIdx.x;
    int h = threadIdx.y;
    int lane = threadIdx.x;
    float f0 = (float)featc[(size_t)(2 * h) * CHSTRIDE + (size_t)v * 64 + lane];
    float f1 = (float)featc[(size_t)(2 * h + 1) * CHSTRIDE + (size_t)v * 64 + lane];
    float sl = f0 * al[h * 128 + lane] + f1 * al[h * 128 + 64 + lane];
    float sr = f0 * ar[h * 128 + lane] + f1 * ar[h * 128 + 64 + lane];
#pragma unroll
    for (int off = 32; off > 0; off >>= 1) {
        sl += __shfl_down(sl, off, 64);
        sr += __shfl_down(sr, off, 64);
    }
    if (lane == 0) { el8[(size_t)v * 8 + h] = sl; er8[(size_t)v * 8 + h] = sr; }
}

// ------------------------ edge softmax weights -----------------------------
// Single pass: unnormalized exp weights (f32, head-major wexp[h*E+pos]) plus
// inv8[v*8+h] = 1/max(sum,1e-9), folded into agg epilogue.

__global__ __launch_bounds__(256, 8) void edge_weight_kernel(
        const float* __restrict__ el8, const float* __restrict__ er8,
        const int* __restrict__ row_off, const int* __restrict__ csr_src,
        float* __restrict__ wexp, float* __restrict__ inv8,
        int H, int n, int E) {
    int wid = threadIdx.x >> 6, lane = threadIdx.x & 63;
    for (int v = blockIdx.x * 4 + wid; v < n; v += 8192) {
        float era[6];
#pragma unroll
        for (int h = 0; h < 6; ++h) era[h] = (h < H) ? er8[(size_t)v * 8 + h] : 0.f;
        int beg = row_off[v], end = row_off[v + 1];
        float lsum[6] = {0.f, 0.f, 0.f, 0.f, 0.f, 0.f};
        for (int pos = beg; pos < end; pos += 64) {
            int cnt = min(64, end - pos);
            int s_l = (lane < cnt) ? csr_src[pos + lane] : 0;
            float4 a = *(const float4*)&el8[(size_t)s_l * 8];
            float2 bq = *(const float2*)&el8[(size_t)s_l * 8 + 4];
            float ee[6] = {a.x, a.y, a.z, a.w, bq.x, bq.y};
#pragma unroll
            for (int h = 0; h < 6; ++h) {
                if (h < H) {
                    float lg = ee[h] + era[h];
                    lg = (lg >= 0.f) ? lg : 0.2f * lg;
                    float wv = __expf(lg);
                    if (lane >= cnt) wv = 0.f;
                    lsum[h] += wv;
                    if (lane < cnt) wexp[(size_t)h * E + pos + lane] = wv;
                }
            }
        }
#pragma unroll
        for (int h = 0; h < 6; ++h)
#pragma unroll
            for (int off = 32; off >= 1; off >>= 1)
                lsum[h] += __shfl_xor(lsum[h], off, 64);
        if (lane == 0) {
#pragma unroll
            for (int h = 0; h < 6; ++h)
                if (h < H) inv8[(size_t)v * 8 + h] = 1.f / fmaxf(lsum[h], 1e-9f);
        }
    }
}

// ------------------------ chunk-sharded aggregation v2 ---------------------
// chunk = blockIdx%8 -> XCD-pinned, gathers L2-resident.
// Wave layout: sub=lane>>3 (edge group), cid=lane&7 (channel slot, 8 ch).
// One half8 gather instr covers 8 edges x 64 channels.

__device__ __forceinline__ void agg_chunk_body(
        const f16* __restrict__ fc, const float* __restrict__ wh,
        const float* __restrict__ inv8, int head,
        const int* __restrict__ row_off, const int* __restrict__ csr_src,
        const f16* __restrict__ res, const float* __restrict__ bias,
        f16* __restrict__ out16, float* __restrict__ out32,
        int n, int width, int act, int chunk, int bic, int vstride,
        int wid, int lane, int* __restrict__ sls, float* __restrict__ wls) {
    int sub = lane >> 3;
    int cid = lane & 7;
    int coff = cid * 8;
    for (int v = bic * 4 + wid; v < n; v += vstride) {
        int beg = row_off[v], end = row_off[v + 1];
        float acc[8] = {0.f, 0.f, 0.f, 0.f, 0.f, 0.f, 0.f, 0.f};
        for (int pos = beg; pos < end; pos += 64) {
            int cnt = min(64, end - pos);
            int s_l = 0; float w_l = 0.f;
            if (lane < cnt) {
                s_l = csr_src[pos + lane];
                w_l = wh[pos + lane];
            }
            sls[lane] = s_l;
            wls[lane] = w_l;
            int ng = (cnt + 7) >> 3;
#pragma unroll 4
            for (int g = 0; g < ng; ++g) {
                int ei = g * 8 + sub;
                int s = sls[ei];
                float w = wls[ei];
                half8 f = *(const half8*)&fc[(size_t)s * 64 + coff];
#pragma unroll
                for (int j = 0; j < 8; ++j) acc[j] += w * (float)f[j];
            }
        }
        // reduce across the 8 edge-groups (lane bits 3,4,5)
#pragma unroll
        for (int mask = 8; mask <= 32; mask <<= 1)
#pragma unroll
            for (int j = 0; j < 8; ++j) acc[j] += __shfl_xor(acc[j], mask, 64);
        float inv = inv8[(size_t)v * 8 + head];
        if (lane < 8) {
            int cb = chunk * 64 + lane * 8;
            size_t base = (size_t)v * width + cb;
            float ox[8];
#pragma unroll
            for (int j = 0; j < 8; ++j) ox[j] = acc[j] * inv;
            if (res) {
                half8 r = *(const half8*)&res[base];
#pragma unroll
                for (int j = 0; j < 8; ++j) ox[j] += (float)r[j];
            }
            float4 bv0 = *(const float4*)&bias[cb];
            float4 bv1 = *(const float4*)&bias[cb + 4];
            ox[0] += bv0.x; ox[1] += bv0.y; ox[2] += bv0.z; ox[3] += bv0.w;
            ox[4] += bv1.x; ox[5] += bv1.y; ox[6] += bv1.z; ox[7] += bv1.w;
            if (act) {
#pragma unroll
                for (int j = 0; j < 8; ++j)
                    ox[j] = (ox[j] > 0.f) ? ox[j] : expm1f(ox[j]);
            }
            if (out16) {
                half8 o;
#pragma unroll
                for (int j = 0; j < 8; ++j) o[j] = (f16)ox[j];
                *(half8*)&out16[base] = o;
            } else {
                *(float4*)&out32[base]     = make_float4(ox[0], ox[1], ox[2], ox[3]);
                *(float4*)&out32[base + 4] = make_float4(ox[4], ox[5], ox[6], ox[7]);
            }
        }
    }
}

__global__ __launch_bounds__(256, 8) void agg_chunk_kernel(
        const f16* __restrict__ featc, const float* __restrict__ wexp,
        const float* __restrict__ inv8,
        const int* __restrict__ row_off, const int* __restrict__ csr_src,
        const f16* __restrict__ res, const float* __restrict__ bias,
        f16* __restrict__ out16, float* __restrict__ out32,
        int n, int nchunks, int width, int E, int act) {
    __shared__ int sls[4][64];
    __shared__ float wls[4][64];
    int wid = threadIdx.x >> 6, lane = threadIdx.x & 63;
    int b = blockIdx.x;
    {   // phase 1: chunks 0..7, 256 blocks each
        int chunk = b & 7;
        agg_chunk_body(featc + (size_t)chunk * CHSTRIDE, wexp + (size_t)(chunk >> 1) * E,
                       inv8, chunk >> 1, row_off, csr_src, res, bias, out16, out32,
                       n, width, act, chunk, b >> 3, 1024, wid, lane, sls[wid], wls[wid]);
    }
    if (nchunks > 8) {   // phase 2: chunks 8..11, 512 blocks each
        int chunk = 8 + (b & 3);
        if (chunk < nchunks)
            agg_chunk_body(featc + (size_t)chunk * CHSTRIDE, wexp + (size_t)(chunk >> 1) * E,
                           inv8, chunk >> 1, row_off, csr_src, res, bias, out16, out32,
                           n, width, act, chunk, b >> 2, 2048, wid, lane, sls[wid], wls[wid]);
    }
}

// ------------------------- head-mean + graph pooling -----------------------

__global__ void mean_pool_kernel(const float* __restrict__ x3,
                                 const int* __restrict__ gid,
                                 float* __restrict__ local,
                                 float* __restrict__ pooled,
                                 float* __restrict__ cnt) {
    int v = blockIdx.x;
    int d = threadIdx.x;
    const float* p = x3 + (size_t)v * 768;
    float s = 0.f;
#pragma unroll
    for (int h = 0; h < 6; ++h) s += p[h * 128 + d];
    s *= (1.f / 6.f);
    local[(size_t)v * 128 + d] = s;
    int g = gid[v];
    atomicAdd(&pooled[g * 128 + d], s);
    if (d == 0) atomicAdd(&cnt[g], 1.0f);
}

__global__ void final_mlp_kernel(const float* __restrict__ pooled,
                                 const float* __restrict__ cnt,
                                 const float* __restrict__ Wm,
                                 const float* __restrict__ bm,
                                 float* __restrict__ gout) {
    int g = blockIdx.x;
    int j = threadIdx.x;
    __shared__ float p[128];
    float c = fmaxf(cnt[g], 1.0f);
    p[j] = pooled[g * 128 + j] / c;
    __syncthreads();
    float s = 0.f;
#pragma unroll 16
    for (int k = 0; k < 128; ++k) s += p[k] * Wm[k * 128 + j];
    gout[g * 128 + j] = s + bm[j];
}

// --------------------------------- driver ----------------------------------

extern "C" void kernel_launch(void* const* d_in, const int* in_sizes, int n_in,
                              void* d_out, int out_size, void* d_ws, size_t ws_size,
                              hipStream_t stream) {
    const float* h     = (const float*)d_in[0];
    const int*   src   = (const int*)d_in[2];
    const int*   dst   = (const int*)d_in[3];
    const int*   gid   = (const int*)d_in[4];
    const float* W0    = (const float*)d_in[5];
    const float* al0   = (const float*)d_in[6];
    const float* ar0   = (const float*)d_in[7];
    const float* b0    = (const float*)d_in[8];
    const float* W1    = (const float*)d_in[9];
    const float* al1   = (const float*)d_in[10];
    const float* ar1   = (const float*)d_in[11];
    const float* b1    = (const float*)d_in[12];
    const float* W2    = (const float*)d_in[13];
    const float* al2   = (const float*)d_in[14];
    const float* ar2   = (const float*)d_in[15];
    const float* b2    = (const float*)d_in[16];
    const float* resW2 = (const float*)d_in[17];
    const float* Wm    = (const float*)d_in[18];
    const float* bm    = (const float*)d_in[19];

    const int n = in_sizes[0] / 128;   // 20000
    const int E = in_sizes[2];         // 320000

    size_t off = 0;
    auto take = [&](size_t bytes) -> void* {
        void* p = (char*)d_ws + off;
        off = (off + bytes + 255) & ~(size_t)255;
        return p;
    };
    f16* h16     = (f16*)take((size_t)M_PAD * 128 * 2);
    f16* Wt0     = (f16*)take((size_t)512 * 128 * 2);
    f16* Wt1     = (f16*)take((size_t)512 * 512 * 2);
    f16* Wt2cat  = (f16*)take((size_t)1536 * 512 * 2);    // [W2^T ; resW2^T]
    f16* featc   = (f16*)take((size_t)12 * CHSTRIDE * 2); // chunk-major feat
    f16* res2    = (f16*)take((size_t)M_PAD * 768 * 2);   // row-major residual L2
    f16* x1_16   = (f16*)take((size_t)M_PAD * 512 * 2);
    f16* x2_16   = (f16*)take((size_t)M_PAD * 512 * 2);
    float* x3    = (float*)take((size_t)n * 768 * 4);
    float* wexp  = (float*)take((size_t)6 * E * 4);
    float* inv8  = (float*)take((size_t)n * 8 * 4);
    float* el8   = (float*)take((size_t)n * 8 * 4);
    float* er8   = (float*)take((size_t)n * 8 * 4);
    int* deg     = (int*)take((size_t)n * 4);
    int* row_off = (int*)take((size_t)(n + 1) * 4);
    int* fillc   = (int*)take((size_t)n * 4);
    int* csr_src = (int*)take((size_t)E * 4);
    float* pooled = (float*)take(64 * 128 * 4);
    float* cnt    = (float*)take(64 * 4);

    float* out_local  = (float*)d_out;
    float* out_global = (float*)d_out + (size_t)n * 128;

    hipMemsetAsync(deg, 0, (size_t)n * 4, stream);
    hipMemsetAsync(fillc, 0, (size_t)n * 4, stream);
    hipMemsetAsync(pooled, 0, 64 * 128 * 4, stream);
    hipMemsetAsync(cnt, 0, 64 * 4, stream);
    hipMemsetAsync(x1_16 + (size_t)n * 512, 0, (size_t)(M_PAD - n) * 512 * 2, stream);
    hipMemsetAsync(x2_16 + (size_t)n * 512, 0, (size_t)(M_PAD - n) * 512 * 2, stream);

    {
        long nv = (long)n * 128, nt = (long)M_PAD * 128;
        cvt_pad_kernel<<<(int)((nt / 4 + 255) / 256), 256, 0, stream>>>(h, h16, nv, nt);
    }
    transpose_cvt_kernel<<<dim3(512 / 32, 128 / 32), dim3(32, 8), 0, stream>>>(W0, Wt0, 128, 512);
    transpose_cvt_kernel<<<dim3(512 / 32, 512 / 32), dim3(32, 8), 0, stream>>>(W1, Wt1, 512, 512);
    transpose_cvt_kernel<<<dim3(768 / 32, 512 / 32), dim3(32, 8), 0, stream>>>(W2, Wt2cat, 512, 768);
    transpose_cvt_kernel<<<dim3(768 / 32, 512 / 32), dim3(32, 8), 0, stream>>>(resW2, Wt2cat + (size_t)768 * 512, 512, 768);

    deg_kernel<<<(E + 255) / 256, 256, 0, stream>>>(dst, deg, E);
    scan_kernel<<<1, 1024, 0, stream>>>(deg, row_off, n);
    fill_kernel<<<(E + 255) / 256, 256, 0, stream>>>(src, dst, row_off, fillc, csr_src, E);

    const int gy = M_PAD / 128;

    // --- layer 0: feat = h16 @ W0 (8 chunks), H=4, no res, elu ---
    gemm16_kernel<<<dim3(512 / 128, gy), 256, 0, stream>>>(h16, Wt0, featc, nullptr, 512, 128, 512);
    attn_logits_kernel<<<n, dim3(64, 4), 0, stream>>>(featc, al0, ar0, el8, er8);
    edge_weight_kernel<<<2048, 256, 0, stream>>>(el8, er8, row_off, csr_src, wexp, inv8, 4, n, E);
    agg_chunk_kernel<<<2048, 256, 0, stream>>>(featc, wexp, inv8, row_off, csr_src,
                                               nullptr, b0, x1_16, nullptr, n, 8, 512, E, 1);
    // --- layer 1: feat = x1 @ W1 (8 chunks), H=4, identity res, elu ---
    gemm16_kernel<<<dim3(512 / 128, gy), 256, 0, stream>>>(x1_16, Wt1, featc, nullptr, 512, 512, 512);
    attn_logits_kernel<<<n, dim3(64, 4), 0, stream>>>(featc, al1, ar1, el8, er8);
    edge_weight_kernel<<<2048, 256, 0, stream>>>(el8, er8, row_off, csr_src, wexp, inv8, 4, n, E);
    agg_chunk_kernel<<<2048, 256, 0, stream>>>(featc, wexp, inv8, row_off, csr_src,
                                               x1_16, b1, x2_16, nullptr, n, 8, 512, E, 1);
    // --- layer 2: [feat(12 chunks) | res2(row-major)] = x2 @ [W2|resW2], H=6 ---
    gemm16_kernel<<<dim3(1536 / 128, gy), 256, 0, stream>>>(x2_16, Wt2cat, featc, res2, 1536, 512, 768);
    attn_logits_kernel<<<n, dim3(64, 6), 0, stream>>>(featc, al2, ar2, el8, er8);
    edge_weight_kernel<<<2048, 256, 0, stream>>>(el8, er8, row_off, csr_src, wexp, inv8, 6, n, E);
    agg_chunk_kernel<<<2048, 256, 0, stream>>>(featc, wexp, inv8, row_off, csr_src,
                                               res2, b2, nullptr, x3, n, 12, 768, E, 0);
    // --- head mean + pooling + final MLP ---
    mean_pool_kernel<<<n, 128, 0, stream>>>(x3, gid, out_local, pooled, cnt);
    final_mlp_kernel<<<64, 128, 0, stream>>>(pooled, cnt, Wm, bm, out_global);
}

// Round 7
// 746.450 us; speedup vs baseline: 1.3257x; 1.1513x over previous
//
#include <hip/hip_runtime.h>
#include <math.h>

// ---------------------------------------------------------------------------
// GAT 3-layer + pooling, XCD-sharded gather v2 + atomic-free pooling.
//  - feat stored CHUNK-MAJOR: featc[chunk][node][64ch]; chunk = blockIdx%8
//    pins each chunk to one XCD's L2 (FETCH floor 330->65MB, round 5).
//  - agg v2: 8 edges per half8 gather instr, LDS-staged src/weights (round 6).
//  - Pooling: graph_id is SORTED -> segmented reduction (seg offsets via
//    binary search), replacing 2.58M device-scope atomics that serialized
//    mean_pool at 162us (round-6 profile: VALUBusy 0.55%, HBM 4%).
// ---------------------------------------------------------------------------

typedef _Float16 f16;
typedef __attribute__((ext_vector_type(8))) _Float16 half8;
typedef __attribute__((ext_vector_type(4))) _Float16 half4;
typedef __attribute__((ext_vector_type(4))) float float4v;

#define M_PAD 20096        // 20000 rounded up to 128
#define CHSTRIDE ((size_t)M_PAD * 64)

__device__ inline void gload_lds16(const void* g, void* l) {
    __builtin_amdgcn_global_load_lds((const __attribute__((address_space(1))) unsigned*)g,
                                     (__attribute__((address_space(3))) unsigned*)l,
                                     16, 0, 0);
}

// ----------------------------- CSR construction ---------------------------

__global__ __launch_bounds__(256) void deg_kernel(const int* __restrict__ dst,
                                                  int* __restrict__ deg, int E) {
    int e = blockIdx.x * 256 + threadIdx.x;
    if (e < E) atomicAdd(&deg[dst[e]], 1);
}

__global__ __launch_bounds__(1024) void scan_kernel(const int* __restrict__ deg,
                                                    int* __restrict__ row_off, int n) {
    __shared__ int sums[1024];
    int t = threadIdx.x;
    int CH = (n + 1023) >> 10;
    int base = t * CH;
    int s = 0;
    for (int i = 0; i < CH; ++i) { int idx = base + i; if (idx < n) s += deg[idx]; }
    sums[t] = s;
    __syncthreads();
    for (int off = 1; off < 1024; off <<= 1) {
        int v = (t >= off) ? sums[t - off] : 0;
        __syncthreads();
        sums[t] += v;
        __syncthreads();
    }
    int run = (t == 0) ? 0 : sums[t - 1];
    for (int i = 0; i < CH; ++i) {
        int idx = base + i;
        if (idx < n) { row_off[idx] = run; run += deg[idx]; }
    }
    if (t == 1023) row_off[n] = run;
}

__global__ __launch_bounds__(256) void fill_kernel(const int* __restrict__ src,
                                                   const int* __restrict__ dst,
                                                   const int* __restrict__ row_off,
                                                   int* __restrict__ fill,
                                                   int* __restrict__ csr_src, int E) {
    int e = blockIdx.x * 256 + threadIdx.x;
    if (e < E) {
        int d = dst[e];
        int pos = row_off[d] + atomicAdd(&fill[d], 1);
        csr_src[pos] = src[e];
    }
}

// ------------------------------ converts -----------------------------------

__global__ __launch_bounds__(256) void cvt_pad_kernel(const float* __restrict__ x,
                                                      f16* __restrict__ y,
                                                      long n_valid, long n_total) {
    long i = ((long)blockIdx.x * 256 + threadIdx.x) * 4;
    if (i >= n_total) return;
    float4 v = make_float4(0.f, 0.f, 0.f, 0.f);
    if (i < n_valid) v = *(const float4*)&x[i];
    half4 o; o[0] = (f16)v.x; o[1] = (f16)v.y; o[2] = (f16)v.z; o[3] = (f16)v.w;
    *(half4*)&y[i] = o;
}

// Wt[n][k] = (f16) W[k][n].  K,N multiples of 32.  block (32,8)
__global__ __launch_bounds__(256) void transpose_cvt_kernel(const float* __restrict__ W,
                                                            f16* __restrict__ Wt,
                                                            int K, int N) {
    __shared__ float tile[32][33];
    int n0 = blockIdx.x * 32, k0 = blockIdx.y * 32;
    int tx = threadIdx.x, ty = threadIdx.y;
#pragma unroll
    for (int i = 0; i < 32; i += 8)
        tile[ty + i][tx] = W[(size_t)(k0 + ty + i) * N + n0 + tx];
    __syncthreads();
#pragma unroll
    for (int i = 0; i < 32; i += 8)
        Wt[(size_t)(n0 + ty + i) * K + k0 + tx] = (f16)tile[tx][ty + i];
}

// ------------------------------ fp16 MFMA GEMM -----------------------------
// Cols < nchunk -> chunk-major Cc[chunk][row][64]; cols >= nchunk -> row-major Cr.

__global__ __launch_bounds__(256) void gemm16_kernel(const f16* __restrict__ A,
                                                     const f16* __restrict__ Bt,
                                                     f16* __restrict__ Cc,
                                                     f16* __restrict__ Cr,
                                                     int N, int K, int nchunk) {
    __shared__ f16 As[128 * 32];
    __shared__ f16 Bs[128 * 32];
    int t = threadIdx.x;
    int w = t >> 6;
    int l = t & 63;
    size_t bm = (size_t)blockIdx.y * 128;
    int bn = blockIdx.x * 128;
    int wm = (w & 1) * 64;
    int wn = (w >> 1) * 64;

    int srow = t >> 2;
    int scol = (t & 3) * 8;
    const f16* ag0 = A + (bm + srow) * K + scol;
    const f16* ag1 = A + (bm + 64 + srow) * K + scol;
    const f16* bg0 = Bt + (size_t)(bn + srow) * K + scol;
    const f16* bg1 = Bt + (size_t)(bn + 64 + srow) * K + scol;
    f16* al0 = As + t * 8;
    f16* al1 = As + 2048 + t * 8;
    f16* bl0 = Bs + t * 8;
    f16* bl1 = Bs + 2048 + t * 8;

    float4v acc[4][4];
#pragma unroll
    for (int i = 0; i < 4; ++i)
#pragma unroll
        for (int j = 0; j < 4; ++j) acc[i][j] = (float4v)(0.f);

    int ml = l & 15, q = l >> 4;
    const f16* ap = As + (wm + ml) * 32 + q * 8;
    const f16* bp = Bs + (wn + ml) * 32 + q * 8;

    for (int k0 = 0; k0 < K; k0 += 32) {
        gload_lds16(ag0 + k0, al0);
        gload_lds16(ag1 + k0, al1);
        gload_lds16(bg0 + k0, bl0);
        gload_lds16(bg1 + k0, bl1);
        __syncthreads();
        half8 af[4], bf[4];
#pragma unroll
        for (int mt = 0; mt < 4; ++mt) af[mt] = *(const half8*)(ap + mt * 16 * 32);
#pragma unroll
        for (int nt = 0; nt < 4; ++nt) bf[nt] = *(const half8*)(bp + nt * 16 * 32);
#pragma unroll
        for (int mt = 0; mt < 4; ++mt)
#pragma unroll
            for (int nt = 0; nt < 4; ++nt)
                acc[mt][nt] = __builtin_amdgcn_mfma_f32_16x16x32_f16(bf[nt], af[mt],
                                                                     acc[mt][nt], 0, 0, 0);
        __syncthreads();
    }
#pragma unroll
    for (int mt = 0; mt < 4; ++mt) {
        size_t row = bm + wm + mt * 16 + ml;
#pragma unroll
        for (int nt = 0; nt < 4; ++nt) {
            half4 hv;
#pragma unroll
            for (int r = 0; r < 4; ++r) hv[r] = (f16)acc[mt][nt][r];
            int col = bn + wn + nt * 16 + q * 4;
            if (col < nchunk) {
                *(half4*)&Cc[(size_t)(col >> 6) * CHSTRIDE + row * 64 + (col & 63)] = hv;
            } else {
                *(half4*)&Cr[row * (size_t)(N - nchunk) + (col - nchunk)] = hv;
            }
        }
    }
}

// --------------------------- attention logits ------------------------------

__global__ void attn_logits_kernel(const f16* __restrict__ featc,
                                   const float* __restrict__ al,
                                   const float* __restrict__ ar,
                                   float* __restrict__ el8, float* __restrict__ er8) {
    int v = blockIdx.x;
    int h = threadIdx.y;
    int lane = threadIdx.x;
    float f0 = (float)featc[(size_t)(2 * h) * CHSTRIDE + (size_t)v * 64 + lane];
    float f1 = (float)featc[(size_t)(2 * h + 1) * CHSTRIDE + (size_t)v * 64 + lane];
    float sl = f0 * al[h * 128 + lane] + f1 * al[h * 128 + 64 + lane];
    float sr = f0 * ar[h * 128 + lane] + f1 * ar[h * 128 + 64 + lane];
#pragma unroll
    for (int off = 32; off > 0; off >>= 1) {
        sl += __shfl_down(sl, off, 64);
        sr += __shfl_down(sr, off, 64);
    }
    if (lane == 0) { el8[(size_t)v * 8 + h] = sl; er8[(size_t)v * 8 + h] = sr; }
}

// ------------------------ edge softmax weights -----------------------------

__global__ __launch_bounds__(256, 8) void edge_weight_kernel(
        const float* __restrict__ el8, const float* __restrict__ er8,
        const int* __restrict__ row_off, const int* __restrict__ csr_src,
        float* __restrict__ wexp, float* __restrict__ inv8,
        int H, int n, int E) {
    int wid = threadIdx.x >> 6, lane = threadIdx.x & 63;
    for (int v = blockIdx.x * 4 + wid; v < n; v += 8192) {
        float era[6];
#pragma unroll
        for (int h = 0; h < 6; ++h) era[h] = (h < H) ? er8[(size_t)v * 8 + h] : 0.f;
        int beg = row_off[v], end = row_off[v + 1];
        float lsum[6] = {0.f, 0.f, 0.f, 0.f, 0.f, 0.f};
        for (int pos = beg; pos < end; pos += 64) {
            int cnt = min(64, end - pos);
            int s_l = (lane < cnt) ? csr_src[pos + lane] : 0;
            float4 a = *(const float4*)&el8[(size_t)s_l * 8];
            float2 bq = *(const float2*)&el8[(size_t)s_l * 8 + 4];
            float ee[6] = {a.x, a.y, a.z, a.w, bq.x, bq.y};
#pragma unroll
            for (int h = 0; h < 6; ++h) {
                if (h < H) {
                    float lg = ee[h] + era[h];
                    lg = (lg >= 0.f) ? lg : 0.2f * lg;
                    float wv = __expf(lg);
                    if (lane >= cnt) wv = 0.f;
                    lsum[h] += wv;
                    if (lane < cnt) wexp[(size_t)h * E + pos + lane] = wv;
                }
            }
        }
#pragma unroll
        for (int h = 0; h < 6; ++h)
#pragma unroll
            for (int off = 32; off >= 1; off >>= 1)
                lsum[h] += __shfl_xor(lsum[h], off, 64);
        if (lane == 0) {
#pragma unroll
            for (int h = 0; h < 6; ++h)
                if (h < H) inv8[(size_t)v * 8 + h] = 1.f / fmaxf(lsum[h], 1e-9f);
        }
    }
}

// ------------------------ chunk-sharded aggregation v2 ---------------------

__device__ __forceinline__ void agg_chunk_body(
        const f16* __restrict__ fc, const float* __restrict__ wh,
        const float* __restrict__ inv8, int head,
        const int* __restrict__ row_off, const int* __restrict__ csr_src,
        const f16* __restrict__ res, const float* __restrict__ bias,
        f16* __restrict__ out16, float* __restrict__ out32,
        int n, int width, int act, int chunk, int bic, int vstride,
        int wid, int lane, int* __restrict__ sls, float* __restrict__ wls) {
    int sub = lane >> 3;
    int cid = lane & 7;
    int coff = cid * 8;
    for (int v = bic * 4 + wid; v < n; v += vstride) {
        int beg = row_off[v], end = row_off[v + 1];
        float acc[8] = {0.f, 0.f, 0.f, 0.f, 0.f, 0.f, 0.f, 0.f};
        for (int pos = beg; pos < end; pos += 64) {
            int cnt = min(64, end - pos);
            int s_l = 0; float w_l = 0.f;
            if (lane < cnt) {
                s_l = csr_src[pos + lane];
                w_l = wh[pos + lane];
            }
            sls[lane] = s_l;
            wls[lane] = w_l;
            int ng = (cnt + 7) >> 3;
#pragma unroll 4
            for (int g = 0; g < ng; ++g) {
                int ei = g * 8 + sub;
                int s = sls[ei];
                float w = wls[ei];
                half8 f = *(const half8*)&fc[(size_t)s * 64 + coff];
#pragma unroll
                for (int j = 0; j < 8; ++j) acc[j] += w * (float)f[j];
            }
        }
#pragma unroll
        for (int mask = 8; mask <= 32; mask <<= 1)
#pragma unroll
            for (int j = 0; j < 8; ++j) acc[j] += __shfl_xor(acc[j], mask, 64);
        float inv = inv8[(size_t)v * 8 + head];
        if (lane < 8) {
            int cb = chunk * 64 + lane * 8;
            size_t base = (size_t)v * width + cb;
            float ox[8];
#pragma unroll
            for (int j = 0; j < 8; ++j) ox[j] = acc[j] * inv;
            if (res) {
                half8 r = *(const half8*)&res[base];
#pragma unroll
                for (int j = 0; j < 8; ++j) ox[j] += (float)r[j];
            }
            float4 bv0 = *(const float4*)&bias[cb];
            float4 bv1 = *(const float4*)&bias[cb + 4];
            ox[0] += bv0.x; ox[1] += bv0.y; ox[2] += bv0.z; ox[3] += bv0.w;
            ox[4] += bv1.x; ox[5] += bv1.y; ox[6] += bv1.z; ox[7] += bv1.w;
            if (act) {
#pragma unroll
                for (int j = 0; j < 8; ++j)
                    ox[j] = (ox[j] > 0.f) ? ox[j] : expm1f(ox[j]);
            }
            if (out16) {
                half8 o;
#pragma unroll
                for (int j = 0; j < 8; ++j) o[j] = (f16)ox[j];
                *(half8*)&out16[base] = o;
            } else {
                *(float4*)&out32[base]     = make_float4(ox[0], ox[1], ox[2], ox[3]);
                *(float4*)&out32[base + 4] = make_float4(ox[4], ox[5], ox[6], ox[7]);
            }
        }
    }
}

__global__ __launch_bounds__(256, 8) void agg_chunk_kernel(
        const f16* __restrict__ featc, const float* __restrict__ wexp,
        const float* __restrict__ inv8,
        const int* __restrict__ row_off, const int* __restrict__ csr_src,
        const f16* __restrict__ res, const float* __restrict__ bias,
        f16* __restrict__ out16, float* __restrict__ out32,
        int n, int nchunks, int width, int E, int act) {
    __shared__ int sls[4][64];
    __shared__ float wls[4][64];
    int wid = threadIdx.x >> 6, lane = threadIdx.x & 63;
    int b = blockIdx.x;
    {   // phase 1: chunks 0..7, 256 blocks each
        int chunk = b & 7;
        agg_chunk_body(featc + (size_t)chunk * CHSTRIDE, wexp + (size_t)(chunk >> 1) * E,
                       inv8, chunk >> 1, row_off, csr_src, res, bias, out16, out32,
                       n, width, act, chunk, b >> 3, 1024, wid, lane, sls[wid], wls[wid]);
    }
    if (nchunks > 8) {   // phase 2: chunks 8..11, 512 blocks each
        int chunk = 8 + (b & 3);
        if (chunk < nchunks)
            agg_chunk_body(featc + (size_t)chunk * CHSTRIDE, wexp + (size_t)(chunk >> 1) * E,
                           inv8, chunk >> 1, row_off, csr_src, res, bias, out16, out32,
                           n, width, act, chunk, b >> 2, 2048, wid, lane, sls[wid], wls[wid]);
    }
}

// ------------------- pooling: segmented (gid is sorted) --------------------

__global__ __launch_bounds__(128) void seg_kernel(const int* __restrict__ gid,
                                                  int* __restrict__ gstart, int n) {
    int g = threadIdx.x;
    if (g > 64) return;
    int lo = 0, hi = n;
    while (lo < hi) {
        int mid = (lo + hi) >> 1;
        if (gid[mid] < g) lo = mid + 1; else hi = mid;
    }
    gstart[g] = lo;
}

// head-mean only; no atomics
__global__ __launch_bounds__(128) void mean_pool_kernel(const float* __restrict__ x3,
                                                        float* __restrict__ local, int n) {
    int v = blockIdx.x;
    int d = threadIdx.x;
    const float* p = x3 + (size_t)v * 768;
    float s = 0.f;
#pragma unroll
    for (int h = 0; h < 6; ++h) s += p[h * 128 + d];
    local[(size_t)v * 128 + d] = s * (1.f / 6.f);
}

// one block per graph: serial segment sum, divide by count
__global__ __launch_bounds__(256) void graph_pool_kernel(const float* __restrict__ local,
                                                         const int* __restrict__ gstart,
                                                         float* __restrict__ pooled) {
    __shared__ float buf[128];
    int g = blockIdx.x;
    int t = threadIdx.x;
    int c = t & 127;
    int sub = t >> 7;   // 0..1
    int beg = gstart[g], end = gstart[g + 1];
    float s = 0.f;
    for (int v = beg + sub; v < end; v += 2) s += local[(size_t)v * 128 + c];
    if (sub == 1) buf[c] = s;
    __syncthreads();
    if (sub == 0) {
        float tot = s + buf[c];
        float cntf = fmaxf((float)(end - beg), 1.f);
        pooled[g * 128 + c] = tot / cntf;
    }
}

__global__ void final_mlp_kernel(const float* __restrict__ pooled,
                                 const float* __restrict__ Wm,
                                 const float* __restrict__ bm,
                                 float* __restrict__ gout) {
    int g = blockIdx.x;
    int j = threadIdx.x;
    __shared__ float p[128];
    p[j] = pooled[g * 128 + j];
    __syncthreads();
    float s = 0.f;
#pragma unroll 16
    for (int k = 0; k < 128; ++k) s += p[k] * Wm[k * 128 + j];
    gout[g * 128 + j] = s + bm[j];
}

// --------------------------------- driver ----------------------------------

extern "C" void kernel_launch(void* const* d_in, const int* in_sizes, int n_in,
                              void* d_out, int out_size, void* d_ws, size_t ws_size,
                              hipStream_t stream) {
    const float* h     = (const float*)d_in[0];
    const int*   src   = (const int*)d_in[2];
    const int*   dst   = (const int*)d_in[3];
    const int*   gid   = (const int*)d_in[4];
    const float* W0    = (const float*)d_in[5];
    const float* al0   = (const float*)d_in[6];
    const float* ar0   = (const float*)d_in[7];
    const float* b0    = (const float*)d_in[8];
    const float* W1    = (const float*)d_in[9];
    const float* al1   = (const float*)d_in[10];
    const float* ar1   = (const float*)d_in[11];
    const float* b1    = (const float*)d_in[12];
    const float* W2    = (const float*)d_in[13];
    const float* al2   = (const float*)d_in[14];
    const float* ar2   = (const float*)d_in[15];
    const float* b2    = (const float*)d_in[16];
    const float* resW2 = (const float*)d_in[17];
    const float* Wm    = (const float*)d_in[18];
    const float* bm    = (const float*)d_in[19];

    const int n = in_sizes[0] / 128;   // 20000
    const int E = in_sizes[2];         // 320000

    size_t off = 0;
    auto take = [&](size_t bytes) -> void* {
        void* p = (char*)d_ws + off;
        off = (off + bytes + 255) & ~(size_t)255;
        return p;
    };
    f16* h16     = (f16*)take((size_t)M_PAD * 128 * 2);
    f16* Wt0     = (f16*)take((size_t)512 * 128 * 2);
    f16* Wt1     = (f16*)take((size_t)512 * 512 * 2);
    f16* Wt2cat  = (f16*)take((size_t)1536 * 512 * 2);    // [W2^T ; resW2^T]
    f16* featc   = (f16*)take((size_t)12 * CHSTRIDE * 2); // chunk-major feat
    f16* res2    = (f16*)take((size_t)M_PAD * 768 * 2);   // row-major residual L2
    f16* x1_16   = (f16*)take((size_t)M_PAD * 512 * 2);
    f16* x2_16   = (f16*)take((size_t)M_PAD * 512 * 2);
    float* x3    = (float*)take((size_t)n * 768 * 4);
    float* wexp  = (float*)take((size_t)6 * E * 4);
    float* inv8  = (float*)take((size_t)n * 8 * 4);
    float* el8   = (float*)take((size_t)n * 8 * 4);
    float* er8   = (float*)take((size_t)n * 8 * 4);
    int* deg     = (int*)take((size_t)n * 4);
    int* row_off = (int*)take((size_t)(n + 1) * 4);
    int* fillc   = (int*)take((size_t)n * 4);
    int* csr_src = (int*)take((size_t)E * 4);
    int* gstart  = (int*)take(65 * 4);
    float* pooled = (float*)take(64 * 128 * 4);

    float* out_local  = (float*)d_out;
    float* out_global = (float*)d_out + (size_t)n * 128;

    hipMemsetAsync(deg, 0, (size_t)n * 4, stream);
    hipMemsetAsync(fillc, 0, (size_t)n * 4, stream);
    hipMemsetAsync(x1_16 + (size_t)n * 512, 0, (size_t)(M_PAD - n) * 512 * 2, stream);
    hipMemsetAsync(x2_16 + (size_t)n * 512, 0, (size_t)(M_PAD - n) * 512 * 2, stream);

    {
        long nv = (long)n * 128, nt = (long)M_PAD * 128;
        cvt_pad_kernel<<<(int)((nt / 4 + 255) / 256), 256, 0, stream>>>(h, h16, nv, nt);
    }
    transpose_cvt_kernel<<<dim3(512 / 32, 128 / 32), dim3(32, 8), 0, stream>>>(W0, Wt0, 128, 512);
    transpose_cvt_kernel<<<dim3(512 / 32, 512 / 32), dim3(32, 8), 0, stream>>>(W1, Wt1, 512, 512);
    transpose_cvt_kernel<<<dim3(768 / 32, 512 / 32), dim3(32, 8), 0, stream>>>(W2, Wt2cat, 512, 768);
    transpose_cvt_kernel<<<dim3(768 / 32, 512 / 32), dim3(32, 8), 0, stream>>>(resW2, Wt2cat + (size_t)768 * 512, 512, 768);

    deg_kernel<<<(E + 255) / 256, 256, 0, stream>>>(dst, deg, E);
    scan_kernel<<<1, 1024, 0, stream>>>(deg, row_off, n);
    fill_kernel<<<(E + 255) / 256, 256, 0, stream>>>(src, dst, row_off, fillc, csr_src, E);
    seg_kernel<<<1, 128, 0, stream>>>(gid, gstart, n);

    const int gy = M_PAD / 128;

    // --- layer 0: feat = h16 @ W0 (8 chunks), H=4, no res, elu ---
    gemm16_kernel<<<dim3(512 / 128, gy), 256, 0, stream>>>(h16, Wt0, featc, nullptr, 512, 128, 512);
    attn_logits_kernel<<<n, dim3(64, 4), 0, stream>>>(featc, al0, ar0, el8, er8);
    edge_weight_kernel<<<2048, 256, 0, stream>>>(el8, er8, row_off, csr_src, wexp, inv8, 4, n, E);
    agg_chunk_kernel<<<2048, 256, 0, stream>>>(featc, wexp, inv8, row_off, csr_src,
                                               nullptr, b0, x1_16, nullptr, n, 8, 512, E, 1);
    // --- layer 1: feat = x1 @ W1 (8 chunks), H=4, identity res, elu ---
    gemm16_kernel<<<dim3(512 / 128, gy), 256, 0, stream>>>(x1_16, Wt1, featc, nullptr, 512, 512, 512);
    attn_logits_kernel<<<n, dim3(64, 4), 0, stream>>>(featc, al1, ar1, el8, er8);
    edge_weight_kernel<<<2048, 256, 0, stream>>>(el8, er8, row_off, csr_src, wexp, inv8, 4, n, E);
    agg_chunk_kernel<<<2048, 256, 0, stream>>>(featc, wexp, inv8, row_off, csr_src,
                                               x1_16, b1, x2_16, nullptr, n, 8, 512, E, 1);
    // --- layer 2: [feat(12 chunks) | res2(row-major)] = x2 @ [W2|resW2], H=6 ---
    gemm16_kernel<<<dim3(1536 / 128, gy), 256, 0, stream>>>(x2_16, Wt2cat, featc, res2, 1536, 512, 768);
    attn_logits_kernel<<<n, dim3(64, 6), 0, stream>>>(featc, al2, ar2, el8, er8);
    edge_weight_kernel<<<2048, 256, 0, stream>>>(el8, er8, row_off, csr_src, wexp, inv8, 6, n, E);
    agg_chunk_kernel<<<2048, 256, 0, stream>>>(featc, wexp, inv8, row_off, csr_src,
                                               res2, b2, nullptr, x3, n, 12, 768, E, 0);
    // --- pooling epilogue (atomic-free) ---
    mean_pool_kernel<<<n, 128, 0, stream>>>(x3, out_local, n);
    graph_pool_kernel<<<64, 256, 0, stream>>>(out_local, gstart, pooled);
    final_mlp_kernel<<<64, 128, 0, stream>>>(pooled, Wm, bm, out_global);
}

// Round 8
// 595.149 us; speedup vs baseline: 1.6628x; 1.2542x over previous
//
#include <hip/hip_runtime.h>
#include <math.h>

// ---------------------------------------------------------------------------
// GAT 3-layer + pooling. XCD-sharded gather v3 (cluster-owns-node).
//  - feat CHUNK-MAJOR: featc[chunk][node][64ch]; chunk = blockIdx%8 pins each
//    2.56MB chunk to one XCD's L2 (round-5: FETCH 330->65MB).
//  - agg v3: wave = 8 clusters x 8 lanes; cluster owns ONE node, iterates its
//    edges; lane slot = 8 channels -> full 128B row per edge, NO cross-cluster
//    reduction, epilogue amortized over 8 nodes (round-7 profile: per-node
//    reduction+epilogue dominated at VALUBusy 59%).
//  - attn logits fused into GEMM epilogue (col-block == one head).
//  - pooling: segmented (graph_id sorted), atomic-free (round 7).
// ---------------------------------------------------------------------------

typedef _Float16 f16;
typedef __attribute__((ext_vector_type(8))) _Float16 half8;
typedef __attribute__((ext_vector_type(4))) _Float16 half4;
typedef __attribute__((ext_vector_type(4))) float float4v;

union U16 { unsigned short u; _Float16 h; };

#define M_PAD 20096        // 20000 rounded up to 128
#define CHSTRIDE ((size_t)M_PAD * 64)

__device__ inline void gload_lds16(const void* g, void* l) {
    __builtin_amdgcn_global_load_lds((const __attribute__((address_space(1))) unsigned*)g,
                                     (__attribute__((address_space(3))) unsigned*)l,
                                     16, 0, 0);
}

// ----------------------------- CSR construction ---------------------------

__global__ __launch_bounds__(256) void deg_kernel(const int* __restrict__ dst,
                                                  int* __restrict__ deg, int E) {
    int e = blockIdx.x * 256 + threadIdx.x;
    if (e < E) atomicAdd(&deg[dst[e]], 1);
}

__global__ __launch_bounds__(1024) void scan_kernel(const int* __restrict__ deg,
                                                    int* __restrict__ row_off, int n) {
    __shared__ int sums[1024];
    int t = threadIdx.x;
    int CH = (n + 1023) >> 10;
    int base = t * CH;
    int s = 0;
    for (int i = 0; i < CH; ++i) { int idx = base + i; if (idx < n) s += deg[idx]; }
    sums[t] = s;
    __syncthreads();
    for (int off = 1; off < 1024; off <<= 1) {
        int v = (t >= off) ? sums[t - off] : 0;
        __syncthreads();
        sums[t] += v;
        __syncthreads();
    }
    int run = (t == 0) ? 0 : sums[t - 1];
    for (int i = 0; i < CH; ++i) {
        int idx = base + i;
        if (idx < n) { row_off[idx] = run; run += deg[idx]; }
    }
    if (t == 1023) row_off[n] = run;
}

__global__ __launch_bounds__(256) void fill_kernel(const int* __restrict__ src,
                                                   const int* __restrict__ dst,
                                                   const int* __restrict__ row_off,
                                                   int* __restrict__ fill,
                                                   int* __restrict__ csr_src, int E) {
    int e = blockIdx.x * 256 + threadIdx.x;
    if (e < E) {
        int d = dst[e];
        int pos = row_off[d] + atomicAdd(&fill[d], 1);
        csr_src[pos] = src[e];
    }
}

// ------------------------------ converts -----------------------------------

__global__ __launch_bounds__(256) void cvt_pad_kernel(const float* __restrict__ x,
                                                      f16* __restrict__ y,
                                                      long n_valid, long n_total) {
    long i = ((long)blockIdx.x * 256 + threadIdx.x) * 4;
    if (i >= n_total) return;
    float4 v = make_float4(0.f, 0.f, 0.f, 0.f);
    if (i < n_valid) v = *(const float4*)&x[i];
    half4 o; o[0] = (f16)v.x; o[1] = (f16)v.y; o[2] = (f16)v.z; o[3] = (f16)v.w;
    *(half4*)&y[i] = o;
}

// Wt[n][k] = (f16) W[k][n].  K,N multiples of 32.  block (32,8)
__global__ __launch_bounds__(256) void transpose_cvt_kernel(const float* __restrict__ W,
                                                            f16* __restrict__ Wt,
                                                            int K, int N) {
    __shared__ float tile[32][33];
    int n0 = blockIdx.x * 32, k0 = blockIdx.y * 32;
    int tx = threadIdx.x, ty = threadIdx.y;
#pragma unroll
    for (int i = 0; i < 32; i += 8)
        tile[ty + i][tx] = W[(size_t)(k0 + ty + i) * N + n0 + tx];
    __syncthreads();
#pragma unroll
    for (int i = 0; i < 32; i += 8)
        Wt[(size_t)(n0 + ty + i) * K + k0 + tx] = (f16)tile[tx][ty + i];
}

// ------------------------------ fp16 MFMA GEMM -----------------------------
// Cols < nchunk -> chunk-major Cc[chunk][row][64]; cols >= nchunk -> row-major Cr.
// If al != nullptr and the 128-col block is a head (bn < nheads*128), the
// epilogue computes el/er for its 128 rows in-register (no extra kernel).

__global__ __launch_bounds__(256) void gemm16_kernel(const f16* __restrict__ A,
                                                     const f16* __restrict__ Bt,
                                                     f16* __restrict__ Cc,
                                                     f16* __restrict__ Cr,
                                                     const float* __restrict__ al,
                                                     const float* __restrict__ ar,
                                                     float* __restrict__ el8,
                                                     float* __restrict__ er8,
                                                     int N, int K, int nchunk,
                                                     int nheads, int nvalid) {
    __shared__ f16 As[128 * 32];
    __shared__ f16 Bs[128 * 32];
    __shared__ float elds[2][2][128];   // [el/er][wn-half][row]
    int t = threadIdx.x;
    int w = t >> 6;
    int l = t & 63;
    size_t bm = (size_t)blockIdx.y * 128;
    int bn = blockIdx.x * 128;
    int wm = (w & 1) * 64;
    int wn = (w >> 1) * 64;

    int srow = t >> 2;
    int scol = (t & 3) * 8;
    const f16* ag0 = A + (bm + srow) * K + scol;
    const f16* ag1 = A + (bm + 64 + srow) * K + scol;
    const f16* bg0 = Bt + (size_t)(bn + srow) * K + scol;
    const f16* bg1 = Bt + (size_t)(bn + 64 + srow) * K + scol;
    f16* al0 = As + t * 8;
    f16* al1 = As + 2048 + t * 8;
    f16* bl0 = Bs + t * 8;
    f16* bl1 = Bs + 2048 + t * 8;

    float4v acc[4][4];
#pragma unroll
    for (int i = 0; i < 4; ++i)
#pragma unroll
        for (int j = 0; j < 4; ++j) acc[i][j] = (float4v)(0.f);

    int ml = l & 15, q = l >> 4;
    const f16* ap = As + (wm + ml) * 32 + q * 8;
    const f16* bp = Bs + (wn + ml) * 32 + q * 8;

    for (int k0 = 0; k0 < K; k0 += 32) {
        gload_lds16(ag0 + k0, al0);
        gload_lds16(ag1 + k0, al1);
        gload_lds16(bg0 + k0, bl0);
        gload_lds16(bg1 + k0, bl1);
        __syncthreads();
        half8 af[4], bf[4];
#pragma unroll
        for (int mt = 0; mt < 4; ++mt) af[mt] = *(const half8*)(ap + mt * 16 * 32);
#pragma unroll
        for (int nt = 0; nt < 4; ++nt) bf[nt] = *(const half8*)(bp + nt * 16 * 32);
#pragma unroll
        for (int mt = 0; mt < 4; ++mt)
#pragma unroll
            for (int nt = 0; nt < 4; ++nt)
                acc[mt][nt] = __builtin_amdgcn_mfma_f32_16x16x32_f16(bf[nt], af[mt],
                                                                     acc[mt][nt], 0, 0, 0);
        __syncthreads();
    }
    // C stores
#pragma unroll
    for (int mt = 0; mt < 4; ++mt) {
        size_t row = bm + wm + mt * 16 + ml;
#pragma unroll
        for (int nt = 0; nt < 4; ++nt) {
            half4 hv;
#pragma unroll
            for (int r = 0; r < 4; ++r) hv[r] = (f16)acc[mt][nt][r];
            int col = bn + wn + nt * 16 + q * 4;
            if (col < nchunk) {
                *(half4*)&Cc[(size_t)(col >> 6) * CHSTRIDE + row * 64 + (col & 63)] = hv;
            } else {
                *(half4*)&Cr[row * (size_t)(N - nchunk) + (col - nchunk)] = hv;
            }
        }
    }
    // fused attention logits (block column == one head)
    if (al != nullptr && bn < nheads * 128) {
        int hh = bn >> 7;
        float4 a4[4], r4[4];
#pragma unroll
        for (int nt = 0; nt < 4; ++nt) {
            int ci = hh * 128 + wn + nt * 16 + q * 4;
            a4[nt] = *(const float4*)&al[ci];
            r4[nt] = *(const float4*)&ar[ci];
        }
        int wnidx = wn >> 6;
#pragma unroll
        for (int mt = 0; mt < 4; ++mt) {
            float ep = 0.f, rp = 0.f;
#pragma unroll
            for (int nt = 0; nt < 4; ++nt) {
                ep += acc[mt][nt][0] * a4[nt].x + acc[mt][nt][1] * a4[nt].y
                    + acc[mt][nt][2] * a4[nt].z + acc[mt][nt][3] * a4[nt].w;
                rp += acc[mt][nt][0] * r4[nt].x + acc[mt][nt][1] * r4[nt].y
                    + acc[mt][nt][2] * r4[nt].z + acc[mt][nt][3] * r4[nt].w;
            }
            ep += __shfl_xor(ep, 16, 64); ep += __shfl_xor(ep, 32, 64);
            rp += __shfl_xor(rp, 16, 64); rp += __shfl_xor(rp, 32, 64);
            if (q == 0) {
                elds[0][wnidx][wm + mt * 16 + ml] = ep;
                elds[1][wnidx][wm + mt * 16 + ml] = rp;
            }
        }
        __syncthreads();
        int row = t & 127, which = t >> 7;
        long gv = (long)bm + row;
        if (gv < nvalid) {
            float vs = elds[which][0][row] + elds[which][1][row];
            if (which == 0) el8[gv * 8 + hh] = vs;
            else            er8[gv * 8 + hh] = vs;
        }
    }
}

// ------------------------ edge softmax weights -----------------------------
// Single pass: unnormalized exp weights (f16 bits, head-major wexp[h*E+pos])
// plus inv8[v*8+h] = 1/max(sum,1e-9) (f32), applied in the agg epilogue.

__global__ __launch_bounds__(256, 8) void edge_weight_kernel(
        const float* __restrict__ el8, const float* __restrict__ er8,
        const int* __restrict__ row_off, const int* __restrict__ csr_src,
        unsigned short* __restrict__ wexp, float* __restrict__ inv8,
        int H, int n, int E) {
    int wid = threadIdx.x >> 6, lane = threadIdx.x & 63;
    for (int v = blockIdx.x * 4 + wid; v < n; v += 8192) {
        float era[6];
#pragma unroll
        for (int h = 0; h < 6; ++h) era[h] = (h < H) ? er8[(size_t)v * 8 + h] : 0.f;
        int beg = row_off[v], end = row_off[v + 1];
        float lsum[6] = {0.f, 0.f, 0.f, 0.f, 0.f, 0.f};
        for (int pos = beg; pos < end; pos += 64) {
            int cnt = min(64, end - pos);
            int s_l = (lane < cnt) ? csr_src[pos + lane] : 0;
            float4 a = *(const float4*)&el8[(size_t)s_l * 8];
            float2 bq = *(const float2*)&el8[(size_t)s_l * 8 + 4];
            float ee[6] = {a.x, a.y, a.z, a.w, bq.x, bq.y};
#pragma unroll
            for (int h = 0; h < 6; ++h) {
                if (h < H) {
                    float lg = ee[h] + era[h];
                    lg = (lg >= 0.f) ? lg : 0.2f * lg;
                    float wv = __expf(lg);
                    if (lane >= cnt) wv = 0.f;
                    lsum[h] += wv;
                    if (lane < cnt) {
                        U16 uu; uu.h = (f16)wv;
                        wexp[(size_t)h * E + pos + lane] = uu.u;
                    }
                }
            }
        }
#pragma unroll
        for (int h = 0; h < 6; ++h)
#pragma unroll
            for (int off = 32; off >= 1; off >>= 1)
                lsum[h] += __shfl_xor(lsum[h], off, 64);
        if (lane == 0) {
#pragma unroll
            for (int h = 0; h < 6; ++h)
                if (h < H) inv8[(size_t)v * 8 + h] = 1.f / fmaxf(lsum[h], 1e-9f);
        }
    }
}

// ---------------- chunk-sharded aggregation v3 (cluster-owns-node) ---------
// Wave = 8 clusters x 8 lanes. Cluster c owns node v0+c; lane slot j owns
// channels j*8..j*8+7. Per edge: one half8 load covers the full 128B row.
// No cross-cluster reduction; epilogue amortized over 8 nodes.

__device__ __forceinline__ void agg_chunk_body(
        const f16* __restrict__ fc, const unsigned short* __restrict__ wh,
        const float* __restrict__ inv8, int head,
        const int* __restrict__ row_off, const int* __restrict__ csr_src,
        const f16* __restrict__ res, const float* __restrict__ bias,
        f16* __restrict__ out16, float* __restrict__ out32,
        int n, int width, int act, int chunk,
        int wave_id, int wavestride, int lane) {
    int c = lane >> 3;
    int j = lane & 7;
    int coff = j * 8;
    int cb = chunk * 64 + coff;
    float4 bv0 = *(const float4*)&bias[cb];
    float4 bv1 = *(const float4*)&bias[cb + 4];
    int clbase = lane & 56;

    for (int v0 = wave_id * 8; v0 < n; v0 += wavestride * 8) {
        int v = v0 + c;
        bool valid = (v < n);
        int beg = 0, end = 0;
        if (valid) { beg = row_off[v]; end = row_off[v + 1]; }
        int rounds = end - beg;
        rounds = max(rounds, __shfl_xor(rounds, 8, 64));
        rounds = max(rounds, __shfl_xor(rounds, 16, 64));
        rounds = max(rounds, __shfl_xor(rounds, 32, 64));
        float acc[8] = {0.f, 0.f, 0.f, 0.f, 0.f, 0.f, 0.f, 0.f};
        int s_pf = 0, w_pf = 0;
        for (int r = 0; r < rounds; ++r) {
            if ((r & 7) == 0) {   // refill 8-edge prefetch (lane j holds slot j)
                int pidx = beg + r + j;
                bool ok = pidx < end;
                s_pf = ok ? csr_src[pidx] : 0;
                w_pf = ok ? (int)wh[pidx] : 0;
            }
            int srcl = clbase + (r & 7);
            int s  = __shfl(s_pf, srcl, 64);
            int wi = __shfl(w_pf, srcl, 64);
            U16 uu; uu.u = (unsigned short)wi;
            float wv = (float)uu.h;
            half8 f = *(const half8*)&fc[(size_t)s * 64 + coff];
#pragma unroll
            for (int k = 0; k < 8; ++k) acc[k] += wv * (float)f[k];
        }
        if (valid) {
            float inv = inv8[(size_t)v * 8 + head];
            float ox[8];
#pragma unroll
            for (int k = 0; k < 8; ++k) ox[k] = acc[k] * inv;
            size_t base = (size_t)v * width + cb;
            if (res) {
                half8 rr = *(const half8*)&res[base];
#pragma unroll
                for (int k = 0; k < 8; ++k) ox[k] += (float)rr[k];
            }
            ox[0] += bv0.x; ox[1] += bv0.y; ox[2] += bv0.z; ox[3] += bv0.w;
            ox[4] += bv1.x; ox[5] += bv1.y; ox[6] += bv1.z; ox[7] += bv1.w;
            if (act) {
#pragma unroll
                for (int k = 0; k < 8; ++k)
                    ox[k] = (ox[k] > 0.f) ? ox[k] : expm1f(ox[k]);
            }
            if (out16) {
                half8 o;
#pragma unroll
                for (int k = 0; k < 8; ++k) o[k] = (f16)ox[k];
                *(half8*)&out16[base] = o;
            } else {
                *(float4*)&out32[base]     = make_float4(ox[0], ox[1], ox[2], ox[3]);
                *(float4*)&out32[base + 4] = make_float4(ox[4], ox[5], ox[6], ox[7]);
            }
        }
    }
}

__global__ __launch_bounds__(256, 8) void agg_chunk_kernel(
        const f16* __restrict__ featc, const unsigned short* __restrict__ wexp,
        const float* __restrict__ inv8,
        const int* __restrict__ row_off, const int* __restrict__ csr_src,
        const f16* __restrict__ res, const float* __restrict__ bias,
        f16* __restrict__ out16, float* __restrict__ out32,
        int n, int nchunks, int width, int E, int act) {
    int wid = threadIdx.x >> 6, lane = threadIdx.x & 63;
    int b = blockIdx.x;
    {   // phase 1: chunks 0..7, 256 blocks (1024 waves) each
        int chunk = b & 7;
        agg_chunk_body(featc + (size_t)chunk * CHSTRIDE, wexp + (size_t)(chunk >> 1) * E,
                       inv8, chunk >> 1, row_off, csr_src, res, bias, out16, out32,
                       n, width, act, chunk, (b >> 3) * 4 + wid, 1024, lane);
    }
    if (nchunks > 8) {   // phase 2: chunks 8..11, 512 blocks (2048 waves) each
        int chunk = 8 + (b & 3);
        if (chunk < nchunks)
            agg_chunk_body(featc + (size_t)chunk * CHSTRIDE, wexp + (size_t)(chunk >> 1) * E,
                           inv8, chunk >> 1, row_off, csr_src, res, bias, out16, out32,
                           n, width, act, chunk, (b >> 2) * 4 + wid, 2048, lane);
    }
}

// ------------------- pooling: segmented (gid is sorted) --------------------

__global__ __launch_bounds__(128) void seg_kernel(const int* __restrict__ gid,
                                                  int* __restrict__ gstart, int n) {
    int g = threadIdx.x;
    if (g > 64) return;
    int lo = 0, hi = n;
    while (lo < hi) {
        int mid = (lo + hi) >> 1;
        if (gid[mid] < g) lo = mid + 1; else hi = mid;
    }
    gstart[g] = lo;
}

__global__ __launch_bounds__(128) void mean_pool_kernel(const float* __restrict__ x3,
                                                        float* __restrict__ local, int n) {
    int v = blockIdx.x;
    int d = threadIdx.x;
    const float* p = x3 + (size_t)v * 768;
    float s = 0.f;
#pragma unroll
    for (int h = 0; h < 6; ++h) s += p[h * 128 + d];
    local[(size_t)v * 128 + d] = s * (1.f / 6.f);
}

__global__ __launch_bounds__(256) void graph_pool_kernel(const float* __restrict__ local,
                                                         const int* __restrict__ gstart,
                                                         float* __restrict__ pooled) {
    __shared__ float buf[128];
    int g = blockIdx.x;
    int t = threadIdx.x;
    int c = t & 127;
    int sub = t >> 7;
    int beg = gstart[g], end = gstart[g + 1];
    float s = 0.f;
    for (int v = beg + sub; v < end; v += 2) s += local[(size_t)v * 128 + c];
    if (sub == 1) buf[c] = s;
    __syncthreads();
    if (sub == 0) {
        float tot = s + buf[c];
        float cntf = fmaxf((float)(end - beg), 1.f);
        pooled[g * 128 + c] = tot / cntf;
    }
}

__global__ void final_mlp_kernel(const float* __restrict__ pooled,
                                 const float* __restrict__ Wm,
                                 const float* __restrict__ bm,
                                 float* __restrict__ gout) {
    int g = blockIdx.x;
    int j = threadIdx.x;
    __shared__ float p[128];
    p[j] = pooled[g * 128 + j];
    __syncthreads();
    float s = 0.f;
#pragma unroll 16
    for (int k = 0; k < 128; ++k) s += p[k] * Wm[k * 128 + j];
    gout[g * 128 + j] = s + bm[j];
}

// --------------------------------- driver ----------------------------------

extern "C" void kernel_launch(void* const* d_in, const int* in_sizes, int n_in,
                              void* d_out, int out_size, void* d_ws, size_t ws_size,
                              hipStream_t stream) {
    const float* h     = (const float*)d_in[0];
    const int*   src   = (const int*)d_in[2];
    const int*   dst   = (const int*)d_in[3];
    const int*   gid   = (const int*)d_in[4];
    const float* W0    = (const float*)d_in[5];
    const float* al0   = (const float*)d_in[6];
    const float* ar0   = (const float*)d_in[7];
    const float* b0    = (const float*)d_in[8];
    const float* W1    = (const float*)d_in[9];
    const float* al1   = (const float*)d_in[10];
    const float* ar1   = (const float*)d_in[11];
    const float* b1    = (const float*)d_in[12];
    const float* W2    = (const float*)d_in[13];
    const float* al2   = (const float*)d_in[14];
    const float* ar2   = (const float*)d_in[15];
    const float* b2    = (const float*)d_in[16];
    const float* resW2 = (const float*)d_in[17];
    const float* Wm    = (const float*)d_in[18];
    const float* bm    = (const float*)d_in[19];

    const int n = in_sizes[0] / 128;   // 20000
    const int E = in_sizes[2];         // 320000

    size_t off = 0;
    auto take = [&](size_t bytes) -> void* {
        void* p = (char*)d_ws + off;
        off = (off + bytes + 255) & ~(size_t)255;
        return p;
    };
    f16* h16     = (f16*)take((size_t)M_PAD * 128 * 2);
    f16* Wt0     = (f16*)take((size_t)512 * 128 * 2);
    f16* Wt1     = (f16*)take((size_t)512 * 512 * 2);
    f16* Wt2cat  = (f16*)take((size_t)1536 * 512 * 2);    // [W2^T ; resW2^T]
    f16* featc   = (f16*)take((size_t)12 * CHSTRIDE * 2); // chunk-major feat
    f16* res2    = (f16*)take((size_t)M_PAD * 768 * 2);   // row-major residual L2
    f16* x1_16   = (f16*)take((size_t)M_PAD * 512 * 2);
    f16* x2_16   = (f16*)take((size_t)M_PAD * 512 * 2);
    float* x3    = (float*)take((size_t)n * 768 * 4);
    unsigned short* wexp = (unsigned short*)take((size_t)6 * E * 2);
    float* inv8  = (float*)take((size_t)n * 8 * 4);
    float* el8   = (float*)take((size_t)n * 8 * 4);
    float* er8   = (float*)take((size_t)n * 8 * 4);
    int* deg     = (int*)take((size_t)n * 4);
    int* row_off = (int*)take((size_t)(n + 1) * 4);
    int* fillc   = (int*)take((size_t)n * 4);
    int* csr_src = (int*)take((size_t)E * 4);
    int* gstart  = (int*)take(65 * 4);
    float* pooled = (float*)take(64 * 128 * 4);

    float* out_local  = (float*)d_out;
    float* out_global = (float*)d_out + (size_t)n * 128;

    hipMemsetAsync(deg, 0, (size_t)n * 4, stream);
    hipMemsetAsync(fillc, 0, (size_t)n * 4, stream);
    hipMemsetAsync(x1_16 + (size_t)n * 512, 0, (size_t)(M_PAD - n) * 512 * 2, stream);
    hipMemsetAsync(x2_16 + (size_t)n * 512, 0, (size_t)(M_PAD - n) * 512 * 2, stream);

    {
        long nv = (long)n * 128, nt = (long)M_PAD * 128;
        cvt_pad_kernel<<<(int)((nt / 4 + 255) / 256), 256, 0, stream>>>(h, h16, nv, nt);
    }
    transpose_cvt_kernel<<<dim3(512 / 32, 128 / 32), dim3(32, 8), 0, stream>>>(W0, Wt0, 128, 512);
    transpose_cvt_kernel<<<dim3(512 / 32, 512 / 32), dim3(32, 8), 0, stream>>>(W1, Wt1, 512, 512);
    transpose_cvt_kernel<<<dim3(768 / 32, 512 / 32), dim3(32, 8), 0, stream>>>(W2, Wt2cat, 512, 768);
    transpose_cvt_kernel<<<dim3(768 / 32, 512 / 32), dim3(32, 8), 0, stream>>>(resW2, Wt2cat + (size_t)768 * 512, 512, 768);

    deg_kernel<<<(E + 255) / 256, 256, 0, stream>>>(dst, deg, E);
    scan_kernel<<<1, 1024, 0, stream>>>(deg, row_off, n);
    fill_kernel<<<(E + 255) / 256, 256, 0, stream>>>(src, dst, row_off, fillc, csr_src, E);
    seg_kernel<<<1, 128, 0, stream>>>(gid, gstart, n);

    const int gy = M_PAD / 128;

    // --- layer 0: feat = h16 @ W0 (8 chunks) + fused logits, H=4, elu ---
    gemm16_kernel<<<dim3(512 / 128, gy), 256, 0, stream>>>(h16, Wt0, featc, nullptr,
                                                           al0, ar0, el8, er8, 512, 128, 512, 4, n);
    edge_weight_kernel<<<2048, 256, 0, stream>>>(el8, er8, row_off, csr_src, wexp, inv8, 4, n, E);
    agg_chunk_kernel<<<2048, 256, 0, stream>>>(featc, wexp, inv8, row_off, csr_src,
                                               nullptr, b0, x1_16, nullptr, n, 8, 512, E, 1);
    // --- layer 1: feat = x1 @ W1 (8 chunks) + fused logits, identity res, elu ---
    gemm16_kernel<<<dim3(512 / 128, gy), 256, 0, stream>>>(x1_16, Wt1, featc, nullptr,
                                                           al1, ar1, el8, er8, 512, 512, 512, 4, n);
    edge_weight_kernel<<<2048, 256, 0, stream>>>(el8, er8, row_off, csr_src, wexp, inv8, 4, n, E);
    agg_chunk_kernel<<<2048, 256, 0, stream>>>(featc, wexp, inv8, row_off, csr_src,
                                               x1_16, b1, x2_16, nullptr, n, 8, 512, E, 1);
    // --- layer 2: [feat(12 chunks) | res2] = x2 @ [W2|resW2] + fused logits, H=6 ---
    gemm16_kernel<<<dim3(1536 / 128, gy), 256, 0, stream>>>(x2_16, Wt2cat, featc, res2,
                                                            al2, ar2, el8, er8, 1536, 512, 768, 6, n);
    edge_weight_kernel<<<2048, 256, 0, stream>>>(el8, er8, row_off, csr_src, wexp, inv8, 6, n, E);
    agg_chunk_kernel<<<2048, 256, 0, stream>>>(featc, wexp, inv8, row_off, csr_src,
                                               res2, b2, nullptr, x3, n, 12, 768, E, 0);
    // --- pooling epilogue (atomic-free) ---
    mean_pool_kernel<<<n, 128, 0, stream>>>(x3, out_local, n);
    graph_pool_kernel<<<64, 256, 0, stream>>>(out_local, gstart, pooled);
    final_mlp_kernel<<<64, 128, 0, stream>>>(pooled, Wm, bm, out_global);
}